// Round 8
// baseline (288.316 us; speedup 1.0000x reference)
//
#include <hip/hip_runtime.h>
#include <math.h>

#define T_SEQ  1024
#define C_DIM  1024
#define NH_    16
#define H_DIM  64
#define SCL    (0.125f * 1.4426950408889634f)   // 1/sqrt(64) folded with log2e

typedef __bf16 bf16;
typedef __bf16 bf16x4 __attribute__((ext_vector_type(4)));
typedef __bf16 bf16x8 __attribute__((ext_vector_type(8)));
typedef float  f32x4  __attribute__((ext_vector_type(4)));

template<bool B> struct BC { static constexpr bool value = B; };

#define MFMA16(a, b, c) __builtin_amdgcn_mfma_f32_16x16x32_bf16(a, b, c, 0, 0, 0)

#define GLOAD_LDS16(g, l) __builtin_amdgcn_global_load_lds( \
    (const __attribute__((address_space(1))) void*)(g),     \
    (__attribute__((address_space(3))) void*)(l), 16, 0, 0)

__device__ __forceinline__ bf16x8 neg8(bf16x8 x) {
    union { bf16x8 v; unsigned int u[4]; } t;
    t.v = x;
    t.u[0] ^= 0x80008000u; t.u[1] ^= 0x80008000u;
    t.u[2] ^= 0x80008000u; t.u[3] ^= 0x80008000u;
    return t.v;
}

// fragment read from XOR-8-chunk-swizzled [rows][64] bf16 plane
__device__ __forceinline__ bf16x8 frag_sw(const bf16* plane, int row, int chunk) {
    int c = chunk ^ (row & 7);
    return *(const bf16x8*)&plane[row * 64 + c * 8];
}
// [rows][32] plane, swizzle c = chunk ^ ((row>>1)&3) — qkv form.
// Staged via sc4q = ((lane&3)^((lane>>3)&3))*8.
__device__ __forceinline__ bf16x8 frag_sw4b(const bf16* plane, int row, int chunk) {
    int c = chunk ^ ((row >> 1) & 3);
    return *(const bf16x8*)&plane[row * 32 + c * 8];
}

// ---------------------------------------------------------------------------
// splits: fp32 complex [R][1024][2] -> bf16 planes (re, im), 8 complex/thread.
// z==5 builds the RoPE phasor table.
// ---------------------------------------------------------------------------
__global__ __launch_bounds__(256)
void split_all(const float* __restrict__ x,  const float* __restrict__ wq,
               const float* __restrict__ wk, const float* __restrict__ wv,
               const float* __restrict__ wo,
               bf16* Xr, bf16* Xi, bf16* Wqr, bf16* Wqi, bf16* Wkr, bf16* Wki,
               bf16* Wvr, bf16* Wvi, bf16* Wor, bf16* Woi,
               float* __restrict__ rope)
{
    int z = blockIdx.y;
    if (z == 5) {
        if (blockIdx.x >= 256) return;
        int idx = blockIdx.x * 256 + threadIdx.x;   // 65536
        int tp = idx >> 6, d = idx & 63;
        float invf = exp2f((float)d * -0.2076205059304601f);
        float fr = (float)tp * invf;
        float sn, cs; sincosf(fr, &sn, &cs);
        *(float2*)&rope[(size_t)idx * 2] = make_float2(cs, sn);
        return;
    }
    if (z > 0 && blockIdx.x >= 512) return;
    const float* in; bf16 *pr, *pi;
    if      (z == 0) { in = x;  pr = Xr;  pi = Xi;  }
    else if (z == 1) { in = wq; pr = Wqr; pi = Wqi; }
    else if (z == 2) { in = wk; pr = Wkr; pi = Wki; }
    else if (z == 3) { in = wv; pr = Wvr; pi = Wvi; }
    else             { in = wo; pr = Wor; pi = Woi; }
    int idx = (blockIdx.x * 256 + threadIdx.x) * 8;   // 8 complex per thread
    bf16x8 r, im;
#pragma unroll
    for (int j = 0; j < 4; j++) {
        float4 v = *(const float4*)(in + (size_t)idx * 2 + j * 4);
        r[2*j]   = (bf16)v.x; im[2*j]   = (bf16)v.y;
        r[2*j+1] = (bf16)v.z; im[2*j+1] = (bf16)v.w;
    }
    *(bf16x8*)(pr + idx) = r;
    *(bf16x8*)(pi + idx) = im;
}

// ---------------------------------------------------------------------------
// FUSED QKV GEMM — round-4 proven form (best measured: ~53.4 us), unchanged.
// Triple-buffered BK=32 (120 KB LDS), 3-phase interleave, counted vmcnt(5).
// ---------------------------------------------------------------------------
__global__ __launch_bounds__(512, 2)
void qkv_gemm(const bf16* __restrict__ Xr, const bf16* __restrict__ Xi,
              const bf16* __restrict__ Wqr, const bf16* __restrict__ Wqi,
              const bf16* __restrict__ Wkr, const bf16* __restrict__ Wki,
              const bf16* __restrict__ Wvr, const bf16* __restrict__ Wvi,
              const float* __restrict__ bq, const float* __restrict__ bk,
              const float* __restrict__ bv, const float* __restrict__ rope,
              bf16* Qr, bf16* Qi, bf16* Kr, bf16* Ki, bf16* Vr, bf16* Vi)
{
    __shared__ __attribute__((aligned(16))) bf16 smem[61440];  // 120 KB: 3 x 20480
    const int t = threadIdx.x, lane = t & 63, wave = t >> 6;
    const int wm = (wave >> 1) * 32, wn = (wave & 1) * 32;
    const int lm = lane & 15, quad = lane >> 4;
    const int lr4 = lane >> 2, sc4q = ((lane & 3) ^ ((lane >> 3) & 3)) * 8;
    const int h = blockIdx.x, m0 = blockIdx.y * 128, n0 = h * 64;

    auto stage1 = [&](bf16* bb_, int j, int k0) {
        int c = wave + 8 * j;                 // 40 chunks of 16 rows x 32 cols
        const bf16* src; bf16* dst;
        if (c < 8)       {                 src = Xr  + (size_t)(m0 + c * 16 + lr4) * C_DIM + k0 + sc4q; dst = bb_ + c * 512; }
        else if (c < 16) { int u = c - 8;  src = Xi  + (size_t)(m0 + u * 16 + lr4) * C_DIM + k0 + sc4q; dst = bb_ + 4096  + u * 512; }
        else if (c < 20) { int u = c - 16; src = Wqr + (size_t)(n0 + u * 16 + lr4) * C_DIM + k0 + sc4q; dst = bb_ + 8192  + u * 512; }
        else if (c < 24) { int u = c - 20; src = Wqi + (size_t)(n0 + u * 16 + lr4) * C_DIM + k0 + sc4q; dst = bb_ + 10240 + u * 512; }
        else if (c < 28) { int u = c - 24; src = Wkr + (size_t)(n0 + u * 16 + lr4) * C_DIM + k0 + sc4q; dst = bb_ + 12288 + u * 512; }
        else if (c < 32) { int u = c - 28; src = Wki + (size_t)(n0 + u * 16 + lr4) * C_DIM + k0 + sc4q; dst = bb_ + 14336 + u * 512; }
        else if (c < 36) { int u = c - 32; src = Wvr + (size_t)(n0 + u * 16 + lr4) * C_DIM + k0 + sc4q; dst = bb_ + 16384 + u * 512; }
        else             { int u = c - 36; src = Wvi + (size_t)(n0 + u * 16 + lr4) * C_DIM + k0 + sc4q; dst = bb_ + 18432 + u * 512; }
        GLOAD_LDS16(src, dst);
    };

    f32x4 accr[3][2][2], acci[3][2][2];
#pragma unroll
    for (int p = 0; p < 3; p++)
#pragma unroll
        for (int i = 0; i < 2; i++)
#pragma unroll
            for (int j = 0; j < 2; j++) { accr[p][i][j] = (f32x4)0.f; acci[p][i][j] = (f32x4)0.f; }

    auto step = [&](auto DOSTAGE, auto DRAIN, int bufsel, int sbsel, int k2) {
        const bf16* buf = smem + bufsel * 20480;
        bf16* sb = smem + sbsel * 20480;
        if constexpr (DRAIN.value)
            asm volatile("s_waitcnt vmcnt(0)\n\ts_barrier" ::: "memory");
        else
            asm volatile("s_waitcnt vmcnt(5)\n\ts_barrier" ::: "memory");

        bf16x8 ar[2], ai_[2], br_[2], bi_[2], bn_[2];
        // ---- phase Q ----
#pragma unroll
        for (int i = 0; i < 2; i++) {
            ar[i]  = frag_sw4b(buf,        wm + i * 16 + lm, quad);
            ai_[i] = frag_sw4b(buf + 4096, wm + i * 16 + lm, quad);
        }
#pragma unroll
        for (int j = 0; j < 2; j++) {
            br_[j] = frag_sw4b(buf + 8192,  wn + j * 16 + lm, quad);
            bi_[j] = frag_sw4b(buf + 10240, wn + j * 16 + lm, quad);
        }
        if constexpr (DOSTAGE.value) { stage1(sb, 0, k2); stage1(sb, 1, k2); }
        asm volatile("s_waitcnt lgkmcnt(0)" ::: "memory");
        __builtin_amdgcn_sched_barrier(0);
        __builtin_amdgcn_s_setprio(1);
#pragma unroll
        for (int j = 0; j < 2; j++) bn_[j] = neg8(bi_[j]);
#pragma unroll
        for (int i = 0; i < 2; i++)
#pragma unroll
            for (int j = 0; j < 2; j++) {
                accr[0][i][j] = MFMA16(ar[i],  br_[j], accr[0][i][j]);
                accr[0][i][j] = MFMA16(ai_[i], bn_[j], accr[0][i][j]);
                acci[0][i][j] = MFMA16(ar[i],  bi_[j], acci[0][i][j]);
                acci[0][i][j] = MFMA16(ai_[i], br_[j], acci[0][i][j]);
            }
        __builtin_amdgcn_s_setprio(0);
        __builtin_amdgcn_s_barrier();
        // ---- phase K ----
#pragma unroll
        for (int j = 0; j < 2; j++) {
            br_[j] = frag_sw4b(buf + 12288, wn + j * 16 + lm, quad);
            bi_[j] = frag_sw4b(buf + 14336, wn + j * 16 + lm, quad);
        }
        if constexpr (DOSTAGE.value) { stage1(sb, 2, k2); stage1(sb, 3, k2); }
        asm volatile("s_waitcnt lgkmcnt(0)" ::: "memory");
        __builtin_amdgcn_sched_barrier(0);
        __builtin_amdgcn_s_setprio(1);
#pragma unroll
        for (int j = 0; j < 2; j++) bn_[j] = neg8(bi_[j]);
#pragma unroll
        for (int i = 0; i < 2; i++)
#pragma unroll
            for (int j = 0; j < 2; j++) {
                accr[1][i][j] = MFMA16(ar[i],  br_[j], accr[1][i][j]);
                accr[1][i][j] = MFMA16(ai_[i], bn_[j], accr[1][i][j]);
                acci[1][i][j] = MFMA16(ar[i],  bi_[j], acci[1][i][j]);
                acci[1][i][j] = MFMA16(ai_[i], br_[j], acci[1][i][j]);
            }
        __builtin_amdgcn_s_setprio(0);
        __builtin_amdgcn_s_barrier();
        // ---- phase V ----
#pragma unroll
        for (int j = 0; j < 2; j++) {
            br_[j] = frag_sw4b(buf + 16384, wn + j * 16 + lm, quad);
            bi_[j] = frag_sw4b(buf + 18432, wn + j * 16 + lm, quad);
        }
        if constexpr (DOSTAGE.value) { stage1(sb, 4, k2); }
        asm volatile("s_waitcnt lgkmcnt(0)" ::: "memory");
        __builtin_amdgcn_sched_barrier(0);
        __builtin_amdgcn_s_setprio(1);
#pragma unroll
        for (int j = 0; j < 2; j++) bn_[j] = neg8(bi_[j]);
#pragma unroll
        for (int i = 0; i < 2; i++)
#pragma unroll
            for (int j = 0; j < 2; j++) {
                accr[2][i][j] = MFMA16(ar[i],  br_[j], accr[2][i][j]);
                accr[2][i][j] = MFMA16(ai_[i], bn_[j], accr[2][i][j]);
                acci[2][i][j] = MFMA16(ar[i],  bi_[j], acci[2][i][j]);
                acci[2][i][j] = MFMA16(ai_[i], br_[j], acci[2][i][j]);
            }
        __builtin_amdgcn_s_setprio(0);
    };

    // prologue: tiles 0,1 fully staged
#pragma unroll
    for (int j = 0; j < 5; j++) stage1(smem,         j, 0);
#pragma unroll
    for (int j = 0; j < 5; j++) stage1(smem + 20480, j, 32);

    for (int base = 0; base < 30; base += 3) {
        step(BC<true>{}, BC<false>{}, 0, 2, (base + 2) * 32);
        step(BC<true>{}, BC<false>{}, 1, 0, (base + 3) * 32);
        step(BC<true>{}, BC<false>{}, 2, 1, (base + 4) * 32);
    }
    step(BC<false>{}, BC<false>{}, 0, 0, 0);
    step(BC<false>{}, BC<true >{}, 1, 0, 0);

    const int bb = m0 >> 10, tbase = m0 & (T_SEQ - 1);

    // ---- Q and K: RoPE + bias, write [B,H,T,64] via LDS bounce ----
#pragma unroll
    for (int p = 0; p < 2; p++) {
        const float* bias = p ? bk : bq;
#pragma unroll
        for (int i = 0; i < 2; i++)
#pragma unroll
            for (int j = 0; j < 2; j++) {
                int d = wn + j * 16 + lm;
                float2 bvv = *(const float2*)&bias[2 * (n0 + d)];
#pragma unroll
                for (int r = 0; r < 4; r++) {
                    int tpos = tbase + wm + i * 16 + quad * 4 + r;
                    float2 ph = *(const float2*)&rope[((size_t)tpos * H_DIM + d) * 2];
                    float yr = accr[p][i][j][r] + bvv.x;
                    float yi = acci[p][i][j][r] + bvv.y;
                    accr[p][i][j][r] = yr * ph.x - yi * ph.y;
                    acci[p][i][j][r] = yr * ph.y + yi * ph.x;
                }
            }
        bf16* dr = (p ? Kr : Qr) + ((size_t)(bb * NH_ + h) * T_SEQ + tbase) * H_DIM;
        bf16* di = (p ? Ki : Qi) + ((size_t)(bb * NH_ + h) * T_SEQ + tbase) * H_DIM;
#pragma unroll
        for (int pass = 0; pass < 2; pass++) {
            __syncthreads();
#pragma unroll
            for (int i = 0; i < 2; i++)
#pragma unroll
                for (int j = 0; j < 2; j++)
#pragma unroll
                    for (int r = 0; r < 4; r++)
                        smem[(wm + i * 16 + quad * 4 + r) * 72 + wn + j * 16 + lm] =
                            (bf16)(pass ? acci[p][i][j][r] : accr[p][i][j][r]);
            __syncthreads();
            bf16* dst = pass ? di : dr;
#pragma unroll
            for (int pp = 0; pp < 2; pp++) {
                int ch = t + 512 * pp;              // 1024 chunks: 128 rows x 8
                int row = ch >> 3, o = (ch & 7) * 8;
                *(bf16x8*)&dst[row * H_DIM + o] = *(const bf16x8*)&smem[row * 72 + o];
            }
        }
    }

    // ---- V: bias, transpose-write [B,H,64,T] via LDS bounce ----
    {
#pragma unroll
        for (int pass = 0; pass < 2; pass++) {
            __syncthreads();
#pragma unroll
            for (int i = 0; i < 2; i++)
#pragma unroll
                for (int j = 0; j < 2; j++) {
                    int d = wn + j * 16 + lm;
                    float2 bvv = *(const float2*)&bv[2 * (n0 + d)];
                    float bb2 = pass ? bvv.y : bvv.x;
                    bf16x4 pk;
#pragma unroll
                    for (int r = 0; r < 4; r++)
                        pk[r] = (bf16)((pass ? acci[2][i][j][r] : accr[2][i][j][r]) + bb2);
                    *(bf16x4*)&smem[d * 136 + wm + i * 16 + quad * 4] = pk;
                }
            __syncthreads();
            bf16* dst = (pass ? Vi : Vr) + ((size_t)(bb * NH_ + h) * H_DIM) * T_SEQ + tbase;
#pragma unroll
            for (int pp = 0; pp < 2; pp++) {
                int ch = t + 512 * pp;              // 1024 chunks: 64 rows x 16
                int row = ch >> 4, o = (ch & 15) * 8;
                *(bf16x8*)&dst[(size_t)row * T_SEQ + o] = *(const bf16x8*)&smem[row * 136 + o];
            }
        }
    }
}

// ---------------------------------------------------------------------------
// 64x64 complex GEMM, BK=64, single-buffer (round-0/1 proven form).
// ---------------------------------------------------------------------------
__global__ __launch_bounds__(256, 4)
void out_gemm(const bf16* __restrict__ Ar, const bf16* __restrict__ Ai,
              const bf16* __restrict__ Br, const bf16* __restrict__ Bi,
              const float* __restrict__ bias, float* __restrict__ Y)
{
    __shared__ __attribute__((aligned(16))) bf16 sm[16384];   // 32 KB
    const int t = threadIdx.x, lane = t & 63, wave = t >> 6;
    const int lm = lane & 15, quad = lane >> 4;
    const int s_lr = lane >> 3, s_c = (lane & 7) ^ s_lr;
    const int wm = (wave >> 1) * 32, wn = (wave & 1) * 32;
    const int m0 = blockIdx.y * 64, n0 = blockIdx.x * 64;

    f32x4 accr[2][2], acci[2][2];
#pragma unroll
    for (int i = 0; i < 2; i++)
#pragma unroll
        for (int j = 0; j < 2; j++) { accr[i][j] = (f32x4)0.f; acci[i][j] = (f32x4)0.f; }

    for (int k0 = 0; k0 < C_DIM; k0 += 64) {
#pragma unroll
        for (int j = 0; j < 8; j++) {
            int c = wave + 4 * j;
            const bf16* src; bf16* dst;
            if (c < 8)       {             src = Ar + (size_t)(m0 + c * 8 + s_lr) * C_DIM + k0 + s_c * 8; dst = sm + c * 512; }
            else if (c < 16) { int u = c - 8;  src = Ai + (size_t)(m0 + u * 8 + s_lr) * C_DIM + k0 + s_c * 8; dst = sm + 4096 + u * 512; }
            else if (c < 24) { int u = c - 16; src = Br + (size_t)(n0 + u * 8 + s_lr) * C_DIM + k0 + s_c * 8; dst = sm + 8192 + u * 512; }
            else             { int u = c - 24; src = Bi + (size_t)(n0 + u * 8 + s_lr) * C_DIM + k0 + s_c * 8; dst = sm + 12288 + u * 512; }
            GLOAD_LDS16(src, dst);
        }
        __syncthreads();
#pragma unroll
        for (int kh = 0; kh < 2; kh++) {
            bf16x8 ar[2], ai_[2], br_[2], bi_[2], bn_[2];
#pragma unroll
            for (int i = 0; i < 2; i++) {
                ar[i]  = frag_sw(sm,        wm + i * 16 + lm, kh * 4 + quad);
                ai_[i] = frag_sw(sm + 4096, wm + i * 16 + lm, kh * 4 + quad);
            }
#pragma unroll
            for (int j = 0; j < 2; j++) {
                br_[j] = frag_sw(sm + 8192,  wn + j * 16 + lm, kh * 4 + quad);
                bi_[j] = frag_sw(sm + 12288, wn + j * 16 + lm, kh * 4 + quad);
                bn_[j] = neg8(bi_[j]);
            }
#pragma unroll
            for (int i = 0; i < 2; i++)
#pragma unroll
                for (int j = 0; j < 2; j++) {
                    accr[i][j] = MFMA16(ar[i],  br_[j], accr[i][j]);
                    accr[i][j] = MFMA16(ai_[i], bn_[j], accr[i][j]);
                    acci[i][j] = MFMA16(ar[i],  bi_[j], acci[i][j]);
                    acci[i][j] = MFMA16(ai_[i], br_[j], acci[i][j]);
                }
        }
        __syncthreads();
    }
#pragma unroll
    for (int i = 0; i < 2; i++)
#pragma unroll
        for (int j = 0; j < 2; j++) {
            int n = n0 + wn + j * 16 + lm;
            float2 bvv = *(const float2*)&bias[2 * n];
#pragma unroll
            for (int r = 0; r < 4; r++) {
                int m = m0 + wm + i * 16 + quad * 4 + r;
                *(float2*)&Y[((size_t)m * C_DIM + n) * 2] =
                    make_float2(accr[i][j][r] + bvv.x, acci[i][j][r] + bvv.y);
            }
        }
}

// ---------------------------------------------------------------------------
// MFMA flash attention v4: BARRIER-FREE main loop with direct-global K/V
// fragment loads. K/V is L2-resident (XCD-pinned by grid (h,q,b)), and the
// MFMA fragment of K ([s-row][8 contig d]) and V^T ([d-row][8 contig s]) is
// 16 B contiguous in the global layout -> load bf16x8 straight to VGPR.
// No LDS staging, no double buffer, no inner-loop __syncthreads: waves run
// free, compiler pipelines next-iter loads under MFMA + softmax.
// Q staged once via LDS (one barrier), held in registers. Merge via LDS.
// ---------------------------------------------------------------------------
__global__ __launch_bounds__(512, 4)
void attn_mfma(const bf16* __restrict__ Qpr, const bf16* __restrict__ Qpi,
               const bf16* __restrict__ Kpr, const bf16* __restrict__ Kpi,
               const bf16* __restrict__ Vtr, const bf16* __restrict__ Vti,
               bf16* __restrict__ ABr, bf16* __restrict__ ABi)
{
    __shared__ __attribute__((aligned(16))) bf16 smem[32768];  // 64 KB
    const int t = threadIdx.x, lane = t & 63, w = t >> 6;
    const int qg = w & 3, sh = w >> 2;
    const int lm = lane & 15, quad = lane >> 4;
    const int h = blockIdx.x;                  // x = head (XCD pin)
    const int q0 = blockIdx.y * 64;            // y = q-tile
    const int b = blockIdx.z;
    const size_t hb = (size_t)(b * NH_ + h) * T_SEQ * H_DIM;
    const int s_lr = lane >> 3, s_c = (lane & 7) ^ s_lr;

    // stage Q (64x64 per plane) into LDS, then hold frags in regs
    {
        const bf16* gq = (sh ? Qpi : Qpr) + hb + (size_t)q0 * H_DIM;
        bf16* lq = smem + 16384 + sh * 4096;
#pragma unroll
        for (int j = 0; j < 2; j++) {
            int cc = qg * 2 + j;
            GLOAD_LDS16(gq + (cc * 8 + s_lr) * H_DIM + s_c * 8, lq + cc * 512);
        }
    }
    __syncthreads();

    bf16x8 qfr[2], qfi[2], nqfr[2];
#pragma unroll
    for (int kh = 0; kh < 2; kh++) {
        qfr[kh]  = frag_sw(smem + 16384, qg * 16 + lm, kh * 4 + quad);
        qfi[kh]  = frag_sw(smem + 20480, qg * 16 + lm, kh * 4 + quad);
        nqfr[kh] = neg8(qfr[kh]);
    }

    const bf16* Kr_ = Kpr + hb;
    const bf16* Ki_ = Kpi + hb;
    const bf16* Vr_ = Vtr + hb;
    const bf16* Vi_ = Vti + hb;

    f32x4 Or[4], Oi[4];
#pragma unroll
    for (int nt = 0; nt < 4; nt++) { Or[nt] = (f32x4)0.f; Oi[nt] = (f32x4)0.f; }
    float lsum = 0.f;
    const int idxA = (((2 * quad) & 3) * 16 + lm) * 4;   // bpermute byte idx
    const int idxB = idxA + 64;
    const bool hisel = quad >= 2;
    const int kcol = quad * 8;                 // 8 contig d per K frag
    const int vcol = quad * 8;                 // 8 contig s per V^T frag

    for (int it = 0; it < 16; it++) {
        const int S = it * 32 + sh * 512;

        // ---- S^T scores (A = K frags direct from global, B = Q regs) ----
        union { unsigned int u[2]; bf16 b[4]; } pk[2];
        float lsA = 0.f, lsB = 0.f;
#pragma unroll
        for (int ct = 0; ct < 2; ct++) {
            f32x4 sre = (f32x4)0.f, sim = (f32x4)0.f;
            const size_t krow = (size_t)(S + ct * 16 + lm) * H_DIM;
            __builtin_amdgcn_s_setprio(1);
#pragma unroll
            for (int kh = 0; kh < 2; kh++) {
                bf16x8 kr = *(const bf16x8*)&Kr_[krow + kh * 32 + kcol];
                bf16x8 ki = *(const bf16x8*)&Ki_[krow + kh * 32 + kcol];
                sre = MFMA16(kr, qfr[kh],  sre);
                sre = MFMA16(ki, qfi[kh],  sre);
                sim = MFMA16(kr, qfi[kh],  sim);
                sim = MFMA16(ki, nqfr[kh], sim);
            }
            __builtin_amdgcn_s_setprio(0);
#pragma unroll
            for (int r = 0; r < 4; r++) {
                float mag2 = fmaf(sre[r], sre[r], sim[r] * sim[r]);
                float p = __builtin_amdgcn_exp2f(__builtin_amdgcn_sqrtf(mag2) * SCL);
                if (ct) lsB += p; else lsA += p;
                pk[ct].b[r] = (bf16)p;
            }
        }
        lsum += lsA + lsB;

        // ---- P C-layout -> A-layout via bpermute (register only) ----
        union { unsigned int u[4]; bf16x8 v; } pf;
        {
            int a0 = __builtin_amdgcn_ds_bpermute(idxA, (int)pk[0].u[0]);
            int a1 = __builtin_amdgcn_ds_bpermute(idxA, (int)pk[1].u[0]);
            int b0 = __builtin_amdgcn_ds_bpermute(idxA, (int)pk[0].u[1]);
            int b1 = __builtin_amdgcn_ds_bpermute(idxA, (int)pk[1].u[1]);
            int c0 = __builtin_amdgcn_ds_bpermute(idxB, (int)pk[0].u[0]);
            int c1 = __builtin_amdgcn_ds_bpermute(idxB, (int)pk[1].u[0]);
            int d0 = __builtin_amdgcn_ds_bpermute(idxB, (int)pk[0].u[1]);
            int d1 = __builtin_amdgcn_ds_bpermute(idxB, (int)pk[1].u[1]);
            pf.u[0] = (unsigned int)(hisel ? a1 : a0);
            pf.u[1] = (unsigned int)(hisel ? b1 : b0);
            pf.u[2] = (unsigned int)(hisel ? c1 : c0);
            pf.u[3] = (unsigned int)(hisel ? d1 : d0);
        }

        // ---- PV: O[q][d] += P @ V^T, V frags direct from global ----
        __builtin_amdgcn_s_setprio(1);
#pragma unroll
        for (int nt = 0; nt < 4; nt++) {
            const size_t vrow = (size_t)(nt * 16 + lm) * T_SEQ + S + vcol;
            bf16x8 vr = *(const bf16x8*)&Vr_[vrow];
            bf16x8 vi = *(const bf16x8*)&Vi_[vrow];
            Or[nt] = MFMA16(pf.v, vr, Or[nt]);
            Oi[nt] = MFMA16(pf.v, vi, Oi[nt]);
        }
        __builtin_amdgcn_s_setprio(0);
    }

    // reduce lsum across quads
    lsum += __shfl_xor(lsum, 16);
    lsum += __shfl_xor(lsum, 32);

    // merge the two s-halves: sh1 dumps to LDS, sh0 adds, normalizes, writes
    __syncthreads();                       // Q-frag reads long done; reuse smem
    float* Of  = (float*)smem;             // 128 rows x 66 floats (~33 KB)
    float* lsc = Of + 128 * 66;            // 64 floats
    if (sh == 1) {
#pragma unroll
        for (int nt = 0; nt < 4; nt++)
#pragma unroll
            for (int r = 0; r < 4; r++) {
                Of[((qg * 2 + 0) * 16 + quad * 4 + r) * 66 + nt * 16 + lm] = Or[nt][r];
                Of[((qg * 2 + 1) * 16 + quad * 4 + r) * 66 + nt * 16 + lm] = Oi[nt][r];
            }
        if (quad == 0) lsc[qg * 16 + lm] = lsum;
    }
    __syncthreads();
    if (sh == 0) {
        float ltot = lsum + lsc[qg * 16 + lm];
        float lv = 1.f / ltot;
        float linv[4];
#pragma unroll
        for (int r = 0; r < 4; r++)
            linv[r] = __shfl(lv, (quad << 4) + quad * 4 + r, 64);
        size_t mbase = (size_t)(b * T_SEQ + q0 + qg * 16 + quad * 4) * C_DIM;
        int colb = h * H_DIM + lm;
#pragma unroll
        for (int nt = 0; nt < 4; nt++)
#pragma unroll
            for (int r = 0; r < 4; r++) {
                float orv = Or[nt][r] + Of[((qg * 2 + 0) * 16 + quad * 4 + r) * 66 + nt * 16 + lm];
                float oiv = Oi[nt][r] + Of[((qg * 2 + 1) * 16 + quad * 4 + r) * 66 + nt * 16 + lm];
                size_t o = mbase + (size_t)r * C_DIM + colb + nt * 16;
                ABr[o] = (bf16)(orv * linv[r]);
                ABi[o] = (bf16)(oiv * linv[r]);
            }
    }
}

// ---------------------------------------------------------------------------
extern "C" void kernel_launch(void* const* d_in, const int* in_sizes, int n_in,
                              void* d_out, int out_size, void* d_ws, size_t ws_size,
                              hipStream_t stream) {
    const float* x  = (const float*)d_in[0];
    const float* wq = (const float*)d_in[1];
    const float* bq = (const float*)d_in[2];
    const float* wk = (const float*)d_in[3];
    const float* bk = (const float*)d_in[4];
    const float* wv = (const float*)d_in[5];
    const float* bv = (const float*)d_in[6];
    const float* wo = (const float*)d_in[7];
    const float* bo = (const float*)d_in[8];

    float* rope = (float*)d_ws;                       // 131072 floats (512 KB)
    bf16* w = (bf16*)(rope + 131072);
    const size_t MSZ = (size_t)2048 * 1024;
    const size_t WSZ = (size_t)1024 * 1024;
    const size_t PSZ = (size_t)2 * NH_ * T_SEQ * H_DIM;

    bf16 *Xr = w, *Xi = Xr + MSZ;
    bf16 *Wqr = Xi + MSZ,  *Wqi = Wqr + WSZ;
    bf16 *Wkr = Wqi + WSZ, *Wki = Wkr + WSZ;
    bf16 *Wvr = Wki + WSZ, *Wvi = Wvr + WSZ;
    bf16 *Wor = Wvi + WSZ, *Woi = Wor + WSZ;
    bf16 *Qr = Woi + WSZ, *Qi = Qr + PSZ;
    bf16 *Kr = Qi + PSZ,  *Ki = Kr + PSZ;
    bf16 *Vr = Ki + PSZ,  *Vi = Vr + PSZ;
    bf16 *ABr = Vi + PSZ, *ABi = ABr + MSZ;

    split_all<<<dim3(1024, 6), 256, 0, stream>>>(x, wq, wk, wv, wo,
        Xr, Xi, Wqr, Wqi, Wkr, Wki, Wvr, Wvi, Wor, Woi, rope);

    qkv_gemm<<<dim3(16, 16), 512, 0, stream>>>(
        Xr, Xi, Wqr, Wqi, Wkr, Wki, Wvr, Wvi, bq, bk, bv, rope,
        Qr, Qi, Kr, Ki, Vr, Vi);

    attn_mfma<<<dim3(16, 16, 2), 512, 0, stream>>>(
        Qr, Qi, Kr, Ki, Vr, Vi, ABr, ABi);

    out_gemm<<<dim3(16, 32), 256, 0, stream>>>(ABr, ABi, Wor, Woi, bo, (float*)d_out);
}

// Round 9
// 205.172 us; speedup vs baseline: 1.4052x; 1.4052x over previous
//
#include <hip/hip_runtime.h>
#include <math.h>

#define T_SEQ  1024
#define C_DIM  1024
#define NH_    16
#define H_DIM  64
#define SCL    (0.125f * 1.4426950408889634f)   // 1/sqrt(64) folded with log2e

typedef __bf16 bf16;
typedef __bf16 bf16x4 __attribute__((ext_vector_type(4)));
typedef __bf16 bf16x8 __attribute__((ext_vector_type(8)));
typedef float  f32x4  __attribute__((ext_vector_type(4)));

template<bool B> struct BC { static constexpr bool value = B; };

#define MFMA16(a, b, c) __builtin_amdgcn_mfma_f32_16x16x32_bf16(a, b, c, 0, 0, 0)

#define GLOAD_LDS16(g, l) __builtin_amdgcn_global_load_lds( \
    (const __attribute__((address_space(1))) void*)(g),     \
    (__attribute__((address_space(3))) void*)(l), 16, 0, 0)

__device__ __forceinline__ bf16x8 neg8(bf16x8 x) {
    union { bf16x8 v; unsigned int u[4]; } t;
    t.v = x;
    t.u[0] ^= 0x80008000u; t.u[1] ^= 0x80008000u;
    t.u[2] ^= 0x80008000u; t.u[3] ^= 0x80008000u;
    return t.v;
}

// fragment read from XOR-8-chunk-swizzled [rows][64] bf16 plane
__device__ __forceinline__ bf16x8 frag_sw(const bf16* plane, int row, int chunk) {
    int c = chunk ^ (row & 7);
    return *(const bf16x8*)&plane[row * 64 + c * 8];
}
// [rows][32] plane, swizzle c = chunk ^ (row&3) — round-0/1 attn form.
// Staged via sc4a = ((lane&3)^((lane>>2)&3))*8.
__device__ __forceinline__ bf16x8 frag_sw4(const bf16* plane, int row, int chunk) {
    int c = chunk ^ (row & 3);
    return *(const bf16x8*)&plane[row * 32 + c * 8];
}
// [rows][32] plane, swizzle c = chunk ^ ((row>>1)&3) — qkv form.
// Staged via sc4q = ((lane&3)^((lane>>3)&3))*8.
__device__ __forceinline__ bf16x8 frag_sw4b(const bf16* plane, int row, int chunk) {
    int c = chunk ^ ((row >> 1) & 3);
    return *(const bf16x8*)&plane[row * 32 + c * 8];
}

// ---------------------------------------------------------------------------
// splits: fp32 complex [R][1024][2] -> bf16 planes (re, im), 8 complex/thread.
// z==5 builds the RoPE phasor table.
// ---------------------------------------------------------------------------
__global__ __launch_bounds__(256)
void split_all(const float* __restrict__ x,  const float* __restrict__ wq,
               const float* __restrict__ wk, const float* __restrict__ wv,
               const float* __restrict__ wo,
               bf16* Xr, bf16* Xi, bf16* Wqr, bf16* Wqi, bf16* Wkr, bf16* Wki,
               bf16* Wvr, bf16* Wvi, bf16* Wor, bf16* Woi,
               float* __restrict__ rope)
{
    int z = blockIdx.y;
    if (z == 5) {
        if (blockIdx.x >= 256) return;
        int idx = blockIdx.x * 256 + threadIdx.x;   // 65536
        int tp = idx >> 6, d = idx & 63;
        float invf = exp2f((float)d * -0.2076205059304601f);
        float fr = (float)tp * invf;
        float sn, cs; sincosf(fr, &sn, &cs);
        *(float2*)&rope[(size_t)idx * 2] = make_float2(cs, sn);
        return;
    }
    if (z > 0 && blockIdx.x >= 512) return;
    const float* in; bf16 *pr, *pi;
    if      (z == 0) { in = x;  pr = Xr;  pi = Xi;  }
    else if (z == 1) { in = wq; pr = Wqr; pi = Wqi; }
    else if (z == 2) { in = wk; pr = Wkr; pi = Wki; }
    else if (z == 3) { in = wv; pr = Wvr; pi = Wvi; }
    else             { in = wo; pr = Wor; pi = Woi; }
    int idx = (blockIdx.x * 256 + threadIdx.x) * 8;   // 8 complex per thread
    bf16x8 r, im;
#pragma unroll
    for (int j = 0; j < 4; j++) {
        float4 v = *(const float4*)(in + (size_t)idx * 2 + j * 4);
        r[2*j]   = (bf16)v.x; im[2*j]   = (bf16)v.y;
        r[2*j+1] = (bf16)v.z; im[2*j+1] = (bf16)v.w;
    }
    *(bf16x8*)(pr + idx) = r;
    *(bf16x8*)(pi + idx) = im;
}

// ---------------------------------------------------------------------------
// FUSED QKV GEMM — round-4 proven form (best measured: ~53.4 us):
//   - one block = (128-row m-tile, 64-col head), q+k+v together (X staged once)
//   - triple-buffered BK=32 (3 x 40 KB = 120 KB LDS), prefetch depth 2
//   - per K-step: 3 phases (q,k,v); each = {ds_read frags || issue 1-2
//     global_load_lds of tile it+2 -> lgkmcnt(0)+sched_barrier(0) ->
//     setprio(1) 16xMFMA setprio(0) -> s_barrier}
//   - ONE counted s_waitcnt vmcnt(5) per K-step; vmcnt(0) only at last step.
// 512 threads = 8 waves (4m x 2n), wave tile 32x32 per proj.
// ---------------------------------------------------------------------------
__global__ __launch_bounds__(512, 2)
void qkv_gemm(const bf16* __restrict__ Xr, const bf16* __restrict__ Xi,
              const bf16* __restrict__ Wqr, const bf16* __restrict__ Wqi,
              const bf16* __restrict__ Wkr, const bf16* __restrict__ Wki,
              const bf16* __restrict__ Wvr, const bf16* __restrict__ Wvi,
              const float* __restrict__ bq, const float* __restrict__ bk,
              const float* __restrict__ bv, const float* __restrict__ rope,
              bf16* Qr, bf16* Qi, bf16* Kr, bf16* Ki, bf16* Vr, bf16* Vi)
{
    __shared__ __attribute__((aligned(16))) bf16 smem[61440];  // 120 KB: 3 x 20480
    const int t = threadIdx.x, lane = t & 63, wave = t >> 6;
    const int wm = (wave >> 1) * 32, wn = (wave & 1) * 32;
    const int lm = lane & 15, quad = lane >> 4;
    const int lr4 = lane >> 2, sc4q = ((lane & 3) ^ ((lane >> 3) & 3)) * 8;
    const int h = blockIdx.x, m0 = blockIdx.y * 128, n0 = h * 64;

    auto stage1 = [&](bf16* bb_, int j, int k0) {
        int c = wave + 8 * j;                 // 40 chunks of 16 rows x 32 cols
        const bf16* src; bf16* dst;
        if (c < 8)       {                 src = Xr  + (size_t)(m0 + c * 16 + lr4) * C_DIM + k0 + sc4q; dst = bb_ + c * 512; }
        else if (c < 16) { int u = c - 8;  src = Xi  + (size_t)(m0 + u * 16 + lr4) * C_DIM + k0 + sc4q; dst = bb_ + 4096  + u * 512; }
        else if (c < 20) { int u = c - 16; src = Wqr + (size_t)(n0 + u * 16 + lr4) * C_DIM + k0 + sc4q; dst = bb_ + 8192  + u * 512; }
        else if (c < 24) { int u = c - 20; src = Wqi + (size_t)(n0 + u * 16 + lr4) * C_DIM + k0 + sc4q; dst = bb_ + 10240 + u * 512; }
        else if (c < 28) { int u = c - 24; src = Wkr + (size_t)(n0 + u * 16 + lr4) * C_DIM + k0 + sc4q; dst = bb_ + 12288 + u * 512; }
        else if (c < 32) { int u = c - 28; src = Wki + (size_t)(n0 + u * 16 + lr4) * C_DIM + k0 + sc4q; dst = bb_ + 14336 + u * 512; }
        else if (c < 36) { int u = c - 32; src = Wvr + (size_t)(n0 + u * 16 + lr4) * C_DIM + k0 + sc4q; dst = bb_ + 16384 + u * 512; }
        else             { int u = c - 36; src = Wvi + (size_t)(n0 + u * 16 + lr4) * C_DIM + k0 + sc4q; dst = bb_ + 18432 + u * 512; }
        GLOAD_LDS16(src, dst);
    };

    f32x4 accr[3][2][2], acci[3][2][2];
#pragma unroll
    for (int p = 0; p < 3; p++)
#pragma unroll
        for (int i = 0; i < 2; i++)
#pragma unroll
            for (int j = 0; j < 2; j++) { accr[p][i][j] = (f32x4)0.f; acci[p][i][j] = (f32x4)0.f; }

    auto step = [&](auto DOSTAGE, auto DRAIN, int bufsel, int sbsel, int k2) {
        const bf16* buf = smem + bufsel * 20480;
        bf16* sb = smem + sbsel * 20480;
        if constexpr (DRAIN.value)
            asm volatile("s_waitcnt vmcnt(0)\n\ts_barrier" ::: "memory");
        else
            asm volatile("s_waitcnt vmcnt(5)\n\ts_barrier" ::: "memory");

        bf16x8 ar[2], ai_[2], br_[2], bi_[2], bn_[2];
        // ---- phase Q ----
#pragma unroll
        for (int i = 0; i < 2; i++) {
            ar[i]  = frag_sw4b(buf,        wm + i * 16 + lm, quad);
            ai_[i] = frag_sw4b(buf + 4096, wm + i * 16 + lm, quad);
        }
#pragma unroll
        for (int j = 0; j < 2; j++) {
            br_[j] = frag_sw4b(buf + 8192,  wn + j * 16 + lm, quad);
            bi_[j] = frag_sw4b(buf + 10240, wn + j * 16 + lm, quad);
        }
        if constexpr (DOSTAGE.value) { stage1(sb, 0, k2); stage1(sb, 1, k2); }
        asm volatile("s_waitcnt lgkmcnt(0)" ::: "memory");
        __builtin_amdgcn_sched_barrier(0);
        __builtin_amdgcn_s_setprio(1);
#pragma unroll
        for (int j = 0; j < 2; j++) bn_[j] = neg8(bi_[j]);
#pragma unroll
        for (int i = 0; i < 2; i++)
#pragma unroll
            for (int j = 0; j < 2; j++) {
                accr[0][i][j] = MFMA16(ar[i],  br_[j], accr[0][i][j]);
                accr[0][i][j] = MFMA16(ai_[i], bn_[j], accr[0][i][j]);
                acci[0][i][j] = MFMA16(ar[i],  bi_[j], acci[0][i][j]);
                acci[0][i][j] = MFMA16(ai_[i], br_[j], acci[0][i][j]);
            }
        __builtin_amdgcn_s_setprio(0);
        __builtin_amdgcn_s_barrier();
        // ---- phase K ----
#pragma unroll
        for (int j = 0; j < 2; j++) {
            br_[j] = frag_sw4b(buf + 12288, wn + j * 16 + lm, quad);
            bi_[j] = frag_sw4b(buf + 14336, wn + j * 16 + lm, quad);
        }
        if constexpr (DOSTAGE.value) { stage1(sb, 2, k2); stage1(sb, 3, k2); }
        asm volatile("s_waitcnt lgkmcnt(0)" ::: "memory");
        __builtin_amdgcn_sched_barrier(0);
        __builtin_amdgcn_s_setprio(1);
#pragma unroll
        for (int j = 0; j < 2; j++) bn_[j] = neg8(bi_[j]);
#pragma unroll
        for (int i = 0; i < 2; i++)
#pragma unroll
            for (int j = 0; j < 2; j++) {
                accr[1][i][j] = MFMA16(ar[i],  br_[j], accr[1][i][j]);
                accr[1][i][j] = MFMA16(ai_[i], bn_[j], accr[1][i][j]);
                acci[1][i][j] = MFMA16(ar[i],  bi_[j], acci[1][i][j]);
                acci[1][i][j] = MFMA16(ai_[i], br_[j], acci[1][i][j]);
            }
        __builtin_amdgcn_s_setprio(0);
        __builtin_amdgcn_s_barrier();
        // ---- phase V ----
#pragma unroll
        for (int j = 0; j < 2; j++) {
            br_[j] = frag_sw4b(buf + 16384, wn + j * 16 + lm, quad);
            bi_[j] = frag_sw4b(buf + 18432, wn + j * 16 + lm, quad);
        }
        if constexpr (DOSTAGE.value) { stage1(sb, 4, k2); }
        asm volatile("s_waitcnt lgkmcnt(0)" ::: "memory");
        __builtin_amdgcn_sched_barrier(0);
        __builtin_amdgcn_s_setprio(1);
#pragma unroll
        for (int j = 0; j < 2; j++) bn_[j] = neg8(bi_[j]);
#pragma unroll
        for (int i = 0; i < 2; i++)
#pragma unroll
            for (int j = 0; j < 2; j++) {
                accr[2][i][j] = MFMA16(ar[i],  br_[j], accr[2][i][j]);
                accr[2][i][j] = MFMA16(ai_[i], bn_[j], accr[2][i][j]);
                acci[2][i][j] = MFMA16(ar[i],  bi_[j], acci[2][i][j]);
                acci[2][i][j] = MFMA16(ai_[i], br_[j], acci[2][i][j]);
            }
        __builtin_amdgcn_s_setprio(0);
    };

    // prologue: tiles 0,1 fully staged
#pragma unroll
    for (int j = 0; j < 5; j++) stage1(smem,         j, 0);
#pragma unroll
    for (int j = 0; j < 5; j++) stage1(smem + 20480, j, 32);

    for (int base = 0; base < 30; base += 3) {
        step(BC<true>{}, BC<false>{}, 0, 2, (base + 2) * 32);
        step(BC<true>{}, BC<false>{}, 1, 0, (base + 3) * 32);
        step(BC<true>{}, BC<false>{}, 2, 1, (base + 4) * 32);
    }
    step(BC<false>{}, BC<false>{}, 0, 0, 0);
    step(BC<false>{}, BC<true >{}, 1, 0, 0);

    const int bb = m0 >> 10, tbase = m0 & (T_SEQ - 1);

    // ---- Q and K: RoPE + bias, write [B,H,T,64] via LDS bounce ----
#pragma unroll
    for (int p = 0; p < 2; p++) {
        const float* bias = p ? bk : bq;
#pragma unroll
        for (int i = 0; i < 2; i++)
#pragma unroll
            for (int j = 0; j < 2; j++) {
                int d = wn + j * 16 + lm;
                float2 bvv = *(const float2*)&bias[2 * (n0 + d)];
#pragma unroll
                for (int r = 0; r < 4; r++) {
                    int tpos = tbase + wm + i * 16 + quad * 4 + r;
                    float2 ph = *(const float2*)&rope[((size_t)tpos * H_DIM + d) * 2];
                    float yr = accr[p][i][j][r] + bvv.x;
                    float yi = acci[p][i][j][r] + bvv.y;
                    accr[p][i][j][r] = yr * ph.x - yi * ph.y;
                    acci[p][i][j][r] = yr * ph.y + yi * ph.x;
                }
            }
        bf16* dr = (p ? Kr : Qr) + ((size_t)(bb * NH_ + h) * T_SEQ + tbase) * H_DIM;
        bf16* di = (p ? Ki : Qi) + ((size_t)(bb * NH_ + h) * T_SEQ + tbase) * H_DIM;
#pragma unroll
        for (int pass = 0; pass < 2; pass++) {
            __syncthreads();
#pragma unroll
            for (int i = 0; i < 2; i++)
#pragma unroll
                for (int j = 0; j < 2; j++)
#pragma unroll
                    for (int r = 0; r < 4; r++)
                        smem[(wm + i * 16 + quad * 4 + r) * 72 + wn + j * 16 + lm] =
                            (bf16)(pass ? acci[p][i][j][r] : accr[p][i][j][r]);
            __syncthreads();
            bf16* dst = pass ? di : dr;
#pragma unroll
            for (int pp = 0; pp < 2; pp++) {
                int ch = t + 512 * pp;              // 1024 chunks: 128 rows x 8
                int row = ch >> 3, o = (ch & 7) * 8;
                *(bf16x8*)&dst[row * H_DIM + o] = *(const bf16x8*)&smem[row * 72 + o];
            }
        }
    }

    // ---- V: bias, transpose-write [B,H,64,T] via LDS bounce ----
    {
#pragma unroll
        for (int pass = 0; pass < 2; pass++) {
            __syncthreads();
#pragma unroll
            for (int i = 0; i < 2; i++)
#pragma unroll
                for (int j = 0; j < 2; j++) {
                    int d = wn + j * 16 + lm;
                    float2 bvv = *(const float2*)&bv[2 * (n0 + d)];
                    float bb2 = pass ? bvv.y : bvv.x;
                    bf16x4 pk;
#pragma unroll
                    for (int r = 0; r < 4; r++)
                        pk[r] = (bf16)((pass ? acci[2][i][j][r] : accr[2][i][j][r]) + bb2);
                    *(bf16x4*)&smem[d * 136 + wm + i * 16 + quad * 4] = pk;
                }
            __syncthreads();
            bf16* dst = (pass ? Vi : Vr) + ((size_t)(bb * NH_ + h) * H_DIM) * T_SEQ + tbase;
#pragma unroll
            for (int pp = 0; pp < 2; pp++) {
                int ch = t + 512 * pp;              // 1024 chunks: 64 rows x 16
                int row = ch >> 4, o = (ch & 15) * 8;
                *(bf16x8*)&dst[(size_t)row * T_SEQ + o] = *(const bf16x8*)&smem[row * 136 + o];
            }
        }
    }
}

// ---------------------------------------------------------------------------
// 64x64 complex GEMM, BK=64, single-buffer (round-0/1 proven form).
// ---------------------------------------------------------------------------
__global__ __launch_bounds__(256, 4)
void out_gemm(const bf16* __restrict__ Ar, const bf16* __restrict__ Ai,
              const bf16* __restrict__ Br, const bf16* __restrict__ Bi,
              const float* __restrict__ bias, float* __restrict__ Y)
{
    __shared__ __attribute__((aligned(16))) bf16 sm[16384];   // 32 KB
    const int t = threadIdx.x, lane = t & 63, wave = t >> 6;
    const int lm = lane & 15, quad = lane >> 4;
    const int s_lr = lane >> 3, s_c = (lane & 7) ^ s_lr;
    const int wm = (wave >> 1) * 32, wn = (wave & 1) * 32;
    const int m0 = blockIdx.y * 64, n0 = blockIdx.x * 64;

    f32x4 accr[2][2], acci[2][2];
#pragma unroll
    for (int i = 0; i < 2; i++)
#pragma unroll
        for (int j = 0; j < 2; j++) { accr[i][j] = (f32x4)0.f; acci[i][j] = (f32x4)0.f; }

    for (int k0 = 0; k0 < C_DIM; k0 += 64) {
#pragma unroll
        for (int j = 0; j < 8; j++) {
            int c = wave + 4 * j;
            const bf16* src; bf16* dst;
            if (c < 8)       {             src = Ar + (size_t)(m0 + c * 8 + s_lr) * C_DIM + k0 + s_c * 8; dst = sm + c * 512; }
            else if (c < 16) { int u = c - 8;  src = Ai + (size_t)(m0 + u * 8 + s_lr) * C_DIM + k0 + s_c * 8; dst = sm + 4096 + u * 512; }
            else if (c < 24) { int u = c - 16; src = Br + (size_t)(n0 + u * 8 + s_lr) * C_DIM + k0 + s_c * 8; dst = sm + 8192 + u * 512; }
            else             { int u = c - 24; src = Bi + (size_t)(n0 + u * 8 + s_lr) * C_DIM + k0 + s_c * 8; dst = sm + 12288 + u * 512; }
            GLOAD_LDS16(src, dst);
        }
        __syncthreads();
#pragma unroll
        for (int kh = 0; kh < 2; kh++) {
            bf16x8 ar[2], ai_[2], br_[2], bi_[2], bn_[2];
#pragma unroll
            for (int i = 0; i < 2; i++) {
                ar[i]  = frag_sw(sm,        wm + i * 16 + lm, kh * 4 + quad);
                ai_[i] = frag_sw(sm + 4096, wm + i * 16 + lm, kh * 4 + quad);
            }
#pragma unroll
            for (int j = 0; j < 2; j++) {
                br_[j] = frag_sw(sm + 8192,  wn + j * 16 + lm, kh * 4 + quad);
                bi_[j] = frag_sw(sm + 12288, wn + j * 16 + lm, kh * 4 + quad);
                bn_[j] = neg8(bi_[j]);
            }
#pragma unroll
            for (int i = 0; i < 2; i++)
#pragma unroll
                for (int j = 0; j < 2; j++) {
                    accr[i][j] = MFMA16(ar[i],  br_[j], accr[i][j]);
                    accr[i][j] = MFMA16(ai_[i], bn_[j], accr[i][j]);
                    acci[i][j] = MFMA16(ar[i],  bi_[j], acci[i][j]);
                    acci[i][j] = MFMA16(ai_[i], br_[j], acci[i][j]);
                }
        }
        __syncthreads();
    }
#pragma unroll
    for (int i = 0; i < 2; i++)
#pragma unroll
        for (int j = 0; j < 2; j++) {
            int n = n0 + wn + j * 16 + lm;
            float2 bvv = *(const float2*)&bias[2 * n];
#pragma unroll
            for (int r = 0; r < 4; r++) {
                int m = m0 + wm + i * 16 + quad * 4 + r;
                *(float2*)&Y[((size_t)m * C_DIM + n) * 2] =
                    make_float2(accr[i][j][r] + bvv.x, acci[i][j][r] + bvv.y);
            }
        }
}

// ---------------------------------------------------------------------------
// MFMA flash attention v3 — round-1 internals; grid (h, q, b) so all 16
// q-blocks of a head land on XCD h%8 and the head's K/V stays L2-resident.
// (Round-7's direct-global variant removed: LDS staging is the decoupling
// buffer that lets tile it+1's loads fly during tile it's compute.)
// ---------------------------------------------------------------------------
__global__ __launch_bounds__(512, 4)
void attn_mfma(const bf16* __restrict__ Qpr, const bf16* __restrict__ Qpi,
               const bf16* __restrict__ Kpr, const bf16* __restrict__ Kpi,
               const bf16* __restrict__ Vtr, const bf16* __restrict__ Vti,
               bf16* __restrict__ ABr, bf16* __restrict__ ABi)
{
    __shared__ __attribute__((aligned(16))) bf16 smem[32768];  // 64 KB
    const int t = threadIdx.x, lane = t & 63, w = t >> 6;
    const int qg = w & 3, sh = w >> 2;
    const int lm = lane & 15, quad = lane >> 4;
    const int h = blockIdx.x;                  // x = head (XCD pin)
    const int q0 = blockIdx.y * 64;            // y = q-tile
    const int b = blockIdx.z;
    const size_t hb = (size_t)(b * NH_ + h) * T_SEQ * H_DIM;
    const int s_lr = lane >> 3, s_c = (lane & 7) ^ s_lr;
    const int lr4 = lane >> 2, sc4a = ((lane & 3) ^ (lr4 & 3)) * 8;

    // stage Q (64x64 per plane) into buf1 region, then hold frags in regs
    {
        const bf16* gq = (sh ? Qpi : Qpr) + hb + (size_t)q0 * H_DIM;
        bf16* lq = smem + 16384 + sh * 4096;
#pragma unroll
        for (int j = 0; j < 2; j++) {
            int cc = qg * 2 + j;
            GLOAD_LDS16(gq + (cc * 8 + s_lr) * H_DIM + s_c * 8, lq + cc * 512);
        }
    }
    __syncthreads();

    bf16x8 qfr[2], qfi[2], nqfr[2];
#pragma unroll
    for (int kh = 0; kh < 2; kh++) {
        qfr[kh]  = frag_sw(smem + 16384, qg * 16 + lm, kh * 4 + quad);
        qfi[kh]  = frag_sw(smem + 20480, qg * 16 + lm, kh * 4 + quad);
        nqfr[kh] = neg8(qfr[kh]);
    }

    // stage tile 0 into buf0 (per-wave plane assignment)
#pragma unroll
    for (int pre = 0; pre < 1; pre++) {
        const int S = sh * 512;
        bf16* bd = smem + sh * 8192;
        if (qg < 2) {
            const bf16* g = (qg ? Kpi : Kpr) + hb + (size_t)S * H_DIM;
            bf16* d = bd + (qg ? 2048 : 0);
#pragma unroll
            for (int cc = 0; cc < 4; cc++)
                GLOAD_LDS16(g + (cc * 8 + s_lr) * H_DIM + s_c * 8, d + cc * 512);
        } else {
            const bf16* g = (qg == 2 ? Vtr : Vti) + hb + S;
            bf16* d = bd + (qg == 2 ? 4096 : 6144);
#pragma unroll
            for (int cc = 0; cc < 4; cc++)
                GLOAD_LDS16(g + (size_t)(cc * 16 + lr4) * T_SEQ + sc4a, d + cc * 512);
        }
    }

    f32x4 Or[4], Oi[4];
#pragma unroll
    for (int nt = 0; nt < 4; nt++) { Or[nt] = (f32x4)0.f; Oi[nt] = (f32x4)0.f; }
    float lsum = 0.f;
    const int idxA = (((2 * quad) & 3) * 16 + lm) * 4;   // bpermute byte idx
    const int idxB = idxA + 64;
    const bool hisel = quad >= 2;

    for (int it = 0; it < 16; it++) {
        __syncthreads();   // drains stage(it) issued last iter
        if (it < 15) {     // stage tile it+1 into the other buffer
            const int S = (it + 1) * 32 + sh * 512;
            bf16* bd = smem + ((it + 1) & 1) * 16384 + sh * 8192;
            if (qg < 2) {
                const bf16* g = (qg ? Kpi : Kpr) + hb + (size_t)S * H_DIM;
                bf16* d = bd + (qg ? 2048 : 0);
#pragma unroll
                for (int cc = 0; cc < 4; cc++)
                    GLOAD_LDS16(g + (cc * 8 + s_lr) * H_DIM + s_c * 8, d + cc * 512);
            } else {
                const bf16* g = (qg == 2 ? Vtr : Vti) + hb + S;
                bf16* d = bd + (qg == 2 ? 4096 : 6144);
#pragma unroll
                for (int cc = 0; cc < 4; cc++)
                    GLOAD_LDS16(g + (size_t)(cc * 16 + lr4) * T_SEQ + sc4a, d + cc * 512);
            }
        }
        const bf16* buf = smem + (it & 1) * 16384 + sh * 8192;

        // ---- S^T scores (A = K frags, B = Q frags), p = exp2(|s|*SCL) ----
        union { unsigned int u[2]; bf16 b[4]; } pk[2];
        float lsA = 0.f, lsB = 0.f;
#pragma unroll
        for (int ct = 0; ct < 2; ct++) {
            f32x4 sre = (f32x4)0.f, sim = (f32x4)0.f;
            __builtin_amdgcn_s_setprio(1);
#pragma unroll
            for (int kh = 0; kh < 2; kh++) {
                bf16x8 kr = frag_sw(buf,        ct * 16 + lm, kh * 4 + quad);
                bf16x8 ki = frag_sw(buf + 2048, ct * 16 + lm, kh * 4 + quad);
                sre = MFMA16(kr, qfr[kh],  sre);
                sre = MFMA16(ki, qfi[kh],  sre);
                sim = MFMA16(kr, qfi[kh],  sim);
                sim = MFMA16(ki, nqfr[kh], sim);
            }
            __builtin_amdgcn_s_setprio(0);
#pragma unroll
            for (int r = 0; r < 4; r++) {
                float mag2 = fmaf(sre[r], sre[r], sim[r] * sim[r]);
                float p = __builtin_amdgcn_exp2f(__builtin_amdgcn_sqrtf(mag2) * SCL);
                if (ct) lsB += p; else lsA += p;
                pk[ct].b[r] = (bf16)p;
            }
        }
        lsum += lsA + lsB;

        // ---- P C-layout -> A-layout via bpermute (no LDS round trip) ----
        union { unsigned int u[4]; bf16x8 v; } pf;
        {
            int a0 = __builtin_amdgcn_ds_bpermute(idxA, (int)pk[0].u[0]);
            int a1 = __builtin_amdgcn_ds_bpermute(idxA, (int)pk[1].u[0]);
            int b0 = __builtin_amdgcn_ds_bpermute(idxA, (int)pk[0].u[1]);
            int b1 = __builtin_amdgcn_ds_bpermute(idxA, (int)pk[1].u[1]);
            int c0 = __builtin_amdgcn_ds_bpermute(idxB, (int)pk[0].u[0]);
            int c1 = __builtin_amdgcn_ds_bpermute(idxB, (int)pk[1].u[0]);
            int d0 = __builtin_amdgcn_ds_bpermute(idxB, (int)pk[0].u[1]);
            int d1 = __builtin_amdgcn_ds_bpermute(idxB, (int)pk[1].u[1]);
            pf.u[0] = (unsigned int)(hisel ? a1 : a0);
            pf.u[1] = (unsigned int)(hisel ? b1 : b0);
            pf.u[2] = (unsigned int)(hisel ? c1 : c0);
            pf.u[3] = (unsigned int)(hisel ? d1 : d0);
        }

        // ---- PV: O[q][d] += P @ V^T ----
        __builtin_amdgcn_s_setprio(1);
#pragma unroll
        for (int nt = 0; nt < 4; nt++) {
            Or[nt] = MFMA16(pf.v, frag_sw4(buf + 4096, nt * 16 + lm, quad), Or[nt]);
            Oi[nt] = MFMA16(pf.v, frag_sw4(buf + 6144, nt * 16 + lm, quad), Oi[nt]);
        }
        __builtin_amdgcn_s_setprio(0);
    }

    // reduce lsum across quads
    lsum += __shfl_xor(lsum, 16);
    lsum += __shfl_xor(lsum, 32);

    // merge the two s-halves: sh1 dumps to LDS, sh0 adds, normalizes, writes
    __syncthreads();
    float* Of  = (float*)smem;             // 128 rows x 66 floats (~33 KB)
    float* lsc = Of + 128 * 66;            // 64 floats
    if (sh == 1) {
#pragma unroll
        for (int nt = 0; nt < 4; nt++)
#pragma unroll
            for (int r = 0; r < 4; r++) {
                Of[((qg * 2 + 0) * 16 + quad * 4 + r) * 66 + nt * 16 + lm] = Or[nt][r];
                Of[((qg * 2 + 1) * 16 + quad * 4 + r) * 66 + nt * 16 + lm] = Oi[nt][r];
            }
        if (quad == 0) lsc[qg * 16 + lm] = lsum;
    }
    __syncthreads();
    if (sh == 0) {
        float ltot = lsum + lsc[qg * 16 + lm];
        float lv = 1.f / ltot;
        float linv[4];
#pragma unroll
        for (int r = 0; r < 4; r++)
            linv[r] = __shfl(lv, (quad << 4) + quad * 4 + r, 64);
        size_t mbase = (size_t)(b * T_SEQ + q0 + qg * 16 + quad * 4) * C_DIM;
        int colb = h * H_DIM + lm;
#pragma unroll
        for (int nt = 0; nt < 4; nt++)
#pragma unroll
            for (int r = 0; r < 4; r++) {
                float orv = Or[nt][r] + Of[((qg * 2 + 0) * 16 + quad * 4 + r) * 66 + nt * 16 + lm];
                float oiv = Oi[nt][r] + Of[((qg * 2 + 1) * 16 + quad * 4 + r) * 66 + nt * 16 + lm];
                size_t o = mbase + (size_t)r * C_DIM + colb + nt * 16;
                ABr[o] = (bf16)(orv * linv[r]);
                ABi[o] = (bf16)(oiv * linv[r]);
            }
    }
}

// ---------------------------------------------------------------------------
extern "C" void kernel_launch(void* const* d_in, const int* in_sizes, int n_in,
                              void* d_out, int out_size, void* d_ws, size_t ws_size,
                              hipStream_t stream) {
    const float* x  = (const float*)d_in[0];
    const float* wq = (const float*)d_in[1];
    const float* bq = (const float*)d_in[2];
    const float* wk = (const float*)d_in[3];
    const float* bk = (const float*)d_in[4];
    const float* wv = (const float*)d_in[5];
    const float* bv = (const float*)d_in[6];
    const float* wo = (const float*)d_in[7];
    const float* bo = (const float*)d_in[8];

    float* rope = (float*)d_ws;                       // 131072 floats (512 KB)
    bf16* w = (bf16*)(rope + 131072);
    const size_t MSZ = (size_t)2048 * 1024;
    const size_t WSZ = (size_t)1024 * 1024;
    const size_t PSZ = (size_t)2 * NH_ * T_SEQ * H_DIM;

    bf16 *Xr = w, *Xi = Xr + MSZ;
    bf16 *Wqr = Xi + MSZ,  *Wqi = Wqr + WSZ;
    bf16 *Wkr = Wqi + WSZ, *Wki = Wkr + WSZ;
    bf16 *Wvr = Wki + WSZ, *Wvi = Wvr + WSZ;
    bf16 *Wor = Wvi + WSZ, *Woi = Wor + WSZ;
    bf16 *Qr = Woi + WSZ, *Qi = Qr + PSZ;
    bf16 *Kr = Qi + PSZ,  *Ki = Kr + PSZ;
    bf16 *Vr = Ki + PSZ,  *Vi = Vr + PSZ;
    bf16 *ABr = Vi + PSZ, *ABi = ABr + MSZ;

    split_all<<<dim3(1024, 6), 256, 0, stream>>>(x, wq, wk, wv, wo,
        Xr, Xi, Wqr, Wqi, Wkr, Wki, Wvr, Wvi, Wor, Woi, rope);

    qkv_gemm<<<dim3(16, 16), 512, 0, stream>>>(
        Xr, Xi, Wqr, Wqi, Wkr, Wki, Wvr, Wvi, bq, bk, bv, rope,
        Qr, Qi, Kr, Ki, Vr, Vi);

    attn_mfma<<<dim3(16, 16, 2), 512, 0, stream>>>(
        Qr, Qi, Kr, Ki, Vr, Vi, ABr, ABi);

    out_gemm<<<dim3(16, 32), 256, 0, stream>>>(ABr, ABi, Wor, Woi, bo, (float*)d_out);
}

// Round 10
// 203.990 us; speedup vs baseline: 1.4134x; 1.0058x over previous
//
#include <hip/hip_runtime.h>
#include <math.h>

#define T_SEQ  1024
#define C_DIM  1024
#define NH_    16
#define H_DIM  64
#define SCL    (0.125f * 1.4426950408889634f)   // 1/sqrt(64) folded with log2e

typedef __bf16 bf16;
typedef __bf16 bf16x4 __attribute__((ext_vector_type(4)));
typedef __bf16 bf16x8 __attribute__((ext_vector_type(8)));
typedef float  f32x4  __attribute__((ext_vector_type(4)));

template<bool B> struct BC { static constexpr bool value = B; };

#define MFMA16(a, b, c) __builtin_amdgcn_mfma_f32_16x16x32_bf16(a, b, c, 0, 0, 0)

#define GLOAD_LDS16(g, l) __builtin_amdgcn_global_load_lds( \
    (const __attribute__((address_space(1))) void*)(g),     \
    (__attribute__((address_space(3))) void*)(l), 16, 0, 0)

__device__ __forceinline__ bf16x8 neg8(bf16x8 x) {
    union { bf16x8 v; unsigned int u[4]; } t;
    t.v = x;
    t.u[0] ^= 0x80008000u; t.u[1] ^= 0x80008000u;
    t.u[2] ^= 0x80008000u; t.u[3] ^= 0x80008000u;
    return t.v;
}

// fragment read from XOR-8-chunk-swizzled [rows][64] bf16 plane
__device__ __forceinline__ bf16x8 frag_sw(const bf16* plane, int row, int chunk) {
    int c = chunk ^ (row & 7);
    return *(const bf16x8*)&plane[row * 64 + c * 8];
}
// [rows][32] plane, swizzle c = chunk ^ (row&3) — round-0/1 attn form.
// Staged via sc4a = ((lane&3)^((lane>>2)&3))*8.
__device__ __forceinline__ bf16x8 frag_sw4(const bf16* plane, int row, int chunk) {
    int c = chunk ^ (row & 3);
    return *(const bf16x8*)&plane[row * 32 + c * 8];
}
// [rows][32] plane, swizzle c = chunk ^ ((row>>1)&3) — qkv form.
// Staged via sc4q = ((lane&3)^((lane>>3)&3))*8.
__device__ __forceinline__ bf16x8 frag_sw4b(const bf16* plane, int row, int chunk) {
    int c = chunk ^ ((row >> 1) & 3);
    return *(const bf16x8*)&plane[row * 32 + c * 8];
}

// ---------------------------------------------------------------------------
// splits: fp32 complex [R][1024][2] -> bf16 planes (re, im), 8 complex/thread.
// z==5 builds the RoPE phasor table.
// ---------------------------------------------------------------------------
__global__ __launch_bounds__(256)
void split_all(const float* __restrict__ x,  const float* __restrict__ wq,
               const float* __restrict__ wk, const float* __restrict__ wv,
               const float* __restrict__ wo,
               bf16* Xr, bf16* Xi, bf16* Wqr, bf16* Wqi, bf16* Wkr, bf16* Wki,
               bf16* Wvr, bf16* Wvi, bf16* Wor, bf16* Woi,
               float* __restrict__ rope)
{
    int z = blockIdx.y;
    if (z == 5) {
        if (blockIdx.x >= 256) return;
        int idx = blockIdx.x * 256 + threadIdx.x;   // 65536
        int tp = idx >> 6, d = idx & 63;
        float invf = exp2f((float)d * -0.2076205059304601f);
        float fr = (float)tp * invf;
        float sn, cs; sincosf(fr, &sn, &cs);
        *(float2*)&rope[(size_t)idx * 2] = make_float2(cs, sn);
        return;
    }
    if (z > 0 && blockIdx.x >= 512) return;
    const float* in; bf16 *pr, *pi;
    if      (z == 0) { in = x;  pr = Xr;  pi = Xi;  }
    else if (z == 1) { in = wq; pr = Wqr; pi = Wqi; }
    else if (z == 2) { in = wk; pr = Wkr; pi = Wki; }
    else if (z == 3) { in = wv; pr = Wvr; pi = Wvi; }
    else             { in = wo; pr = Wor; pi = Woi; }
    int idx = (blockIdx.x * 256 + threadIdx.x) * 8;   // 8 complex per thread
    bf16x8 r, im;
#pragma unroll
    for (int j = 0; j < 4; j++) {
        float4 v = *(const float4*)(in + (size_t)idx * 2 + j * 4);
        r[2*j]   = (bf16)v.x; im[2*j]   = (bf16)v.y;
        r[2*j+1] = (bf16)v.z; im[2*j+1] = (bf16)v.w;
    }
    *(bf16x8*)(pr + idx) = r;
    *(bf16x8*)(pi + idx) = im;
}

// ---------------------------------------------------------------------------
// FUSED QKV GEMM — round-4 pipeline + intra-step ds_read software pipelining:
//   - triple-buffered BK=32 (3 x 40 KB = 120 KB LDS), prefetch depth 2,
//     ONE counted s_waitcnt vmcnt(5) per K-step (entry), vmcnt(0) at last.
//   - NEW: phases Q/K/V have NO intra-step barriers (provably unneeded:
//     reads hit buf[bufsel], staging hits buf[sbsel]!=bufsel, WAR covered by
//     the entry-barrier chain + each wave's own lgkmcnt(0) in phase V).
//   - NEW: B-fragment ds_reads issued one phase EARLY (A+Bq+Bk up front,
//     Bv during phase K) with counted lgkmcnt(4) waits, so LDS latency
//     hides under the preceding MFMA cluster.
// 512 threads = 8 waves (4m x 2n), wave tile 32x32 per proj.
// ---------------------------------------------------------------------------
__global__ __launch_bounds__(512, 2)
void qkv_gemm(const bf16* __restrict__ Xr, const bf16* __restrict__ Xi,
              const bf16* __restrict__ Wqr, const bf16* __restrict__ Wqi,
              const bf16* __restrict__ Wkr, const bf16* __restrict__ Wki,
              const bf16* __restrict__ Wvr, const bf16* __restrict__ Wvi,
              const float* __restrict__ bq, const float* __restrict__ bk,
              const float* __restrict__ bv, const float* __restrict__ rope,
              bf16* Qr, bf16* Qi, bf16* Kr, bf16* Ki, bf16* Vr, bf16* Vi)
{
    __shared__ __attribute__((aligned(16))) bf16 smem[61440];  // 120 KB: 3 x 20480
    const int t = threadIdx.x, lane = t & 63, wave = t >> 6;
    const int wm = (wave >> 1) * 32, wn = (wave & 1) * 32;
    const int lm = lane & 15, quad = lane >> 4;
    const int lr4 = lane >> 2, sc4q = ((lane & 3) ^ ((lane >> 3) & 3)) * 8;
    const int h = blockIdx.x, m0 = blockIdx.y * 128, n0 = h * 64;

    auto stage1 = [&](bf16* bb_, int j, int k0) {
        int c = wave + 8 * j;                 // 40 chunks of 16 rows x 32 cols
        const bf16* src; bf16* dst;
        if (c < 8)       {                 src = Xr  + (size_t)(m0 + c * 16 + lr4) * C_DIM + k0 + sc4q; dst = bb_ + c * 512; }
        else if (c < 16) { int u = c - 8;  src = Xi  + (size_t)(m0 + u * 16 + lr4) * C_DIM + k0 + sc4q; dst = bb_ + 4096  + u * 512; }
        else if (c < 20) { int u = c - 16; src = Wqr + (size_t)(n0 + u * 16 + lr4) * C_DIM + k0 + sc4q; dst = bb_ + 8192  + u * 512; }
        else if (c < 24) { int u = c - 20; src = Wqi + (size_t)(n0 + u * 16 + lr4) * C_DIM + k0 + sc4q; dst = bb_ + 10240 + u * 512; }
        else if (c < 28) { int u = c - 24; src = Wkr + (size_t)(n0 + u * 16 + lr4) * C_DIM + k0 + sc4q; dst = bb_ + 12288 + u * 512; }
        else if (c < 32) { int u = c - 28; src = Wki + (size_t)(n0 + u * 16 + lr4) * C_DIM + k0 + sc4q; dst = bb_ + 14336 + u * 512; }
        else if (c < 36) { int u = c - 32; src = Wvr + (size_t)(n0 + u * 16 + lr4) * C_DIM + k0 + sc4q; dst = bb_ + 16384 + u * 512; }
        else             { int u = c - 36; src = Wvi + (size_t)(n0 + u * 16 + lr4) * C_DIM + k0 + sc4q; dst = bb_ + 18432 + u * 512; }
        GLOAD_LDS16(src, dst);
    };

    f32x4 accr[3][2][2], acci[3][2][2];
#pragma unroll
    for (int p = 0; p < 3; p++)
#pragma unroll
        for (int i = 0; i < 2; i++)
#pragma unroll
            for (int j = 0; j < 2; j++) { accr[p][i][j] = (f32x4)0.f; acci[p][i][j] = (f32x4)0.f; }

    auto step = [&](auto DOSTAGE, auto DRAIN, int bufsel, int sbsel, int k2) {
        const bf16* buf = smem + bufsel * 20480;
        bf16* sb = smem + sbsel * 20480;
        // entry: wait own stage(it) (5 newer = stage(it+1) stay in flight)
        if constexpr (DRAIN.value)
            asm volatile("s_waitcnt vmcnt(0)\n\ts_barrier" ::: "memory");
        else
            asm volatile("s_waitcnt vmcnt(5)\n\ts_barrier" ::: "memory");

        bf16x8 ar[2], ai_[2];
        bf16x8 bqr[2], bqi[2], bkr[2], bki[2], bvr[2], bvi[2], bn_[2];
        // ---- issue A (4), Bq (4), Bk (4) ds_reads in that order; stage 0-1 ----
#pragma unroll
        for (int i = 0; i < 2; i++) {
            ar[i]  = frag_sw4b(buf,        wm + i * 16 + lm, quad);
            ai_[i] = frag_sw4b(buf + 4096, wm + i * 16 + lm, quad);
        }
#pragma unroll
        for (int j = 0; j < 2; j++) {
            bqr[j] = frag_sw4b(buf + 8192,  wn + j * 16 + lm, quad);
            bqi[j] = frag_sw4b(buf + 10240, wn + j * 16 + lm, quad);
        }
#pragma unroll
        for (int j = 0; j < 2; j++) {
            bkr[j] = frag_sw4b(buf + 12288, wn + j * 16 + lm, quad);
            bki[j] = frag_sw4b(buf + 14336, wn + j * 16 + lm, quad);
        }
        if constexpr (DOSTAGE.value) { stage1(sb, 0, k2); stage1(sb, 1, k2); }
        // A+Bq (8 oldest of 12) landed; Bk's 4 may stay in flight
        asm volatile("s_waitcnt lgkmcnt(4)" ::: "memory");
        __builtin_amdgcn_sched_barrier(0);
        __builtin_amdgcn_s_setprio(1);
#pragma unroll
        for (int j = 0; j < 2; j++) bn_[j] = neg8(bqi[j]);
#pragma unroll
        for (int i = 0; i < 2; i++)
#pragma unroll
            for (int j = 0; j < 2; j++) {
                accr[0][i][j] = MFMA16(ar[i],  bqr[j], accr[0][i][j]);
                accr[0][i][j] = MFMA16(ai_[i], bn_[j], accr[0][i][j]);
                acci[0][i][j] = MFMA16(ar[i],  bqi[j], acci[0][i][j]);
                acci[0][i][j] = MFMA16(ai_[i], bqr[j], acci[0][i][j]);
            }
        __builtin_amdgcn_s_setprio(0);
        // ---- issue Bv reads (4); stage 2-3 ----
#pragma unroll
        for (int j = 0; j < 2; j++) {
            bvr[j] = frag_sw4b(buf + 16384, wn + j * 16 + lm, quad);
            bvi[j] = frag_sw4b(buf + 18432, wn + j * 16 + lm, quad);
        }
        if constexpr (DOSTAGE.value) { stage1(sb, 2, k2); stage1(sb, 3, k2); }
        // Bk landed (all but 4 newest = Bv); Bv may stay in flight
        asm volatile("s_waitcnt lgkmcnt(4)" ::: "memory");
        __builtin_amdgcn_sched_barrier(0);
        __builtin_amdgcn_s_setprio(1);
#pragma unroll
        for (int j = 0; j < 2; j++) bn_[j] = neg8(bki[j]);
#pragma unroll
        for (int i = 0; i < 2; i++)
#pragma unroll
            for (int j = 0; j < 2; j++) {
                accr[1][i][j] = MFMA16(ar[i],  bkr[j], accr[1][i][j]);
                accr[1][i][j] = MFMA16(ai_[i], bn_[j], accr[1][i][j]);
                acci[1][i][j] = MFMA16(ar[i],  bki[j], acci[1][i][j]);
                acci[1][i][j] = MFMA16(ai_[i], bkr[j], acci[1][i][j]);
            }
        __builtin_amdgcn_s_setprio(0);
        // ---- stage 4; drain own ds_reads; MFMA V ----
        if constexpr (DOSTAGE.value) { stage1(sb, 4, k2); }
        asm volatile("s_waitcnt lgkmcnt(0)" ::: "memory");
        __builtin_amdgcn_sched_barrier(0);
        __builtin_amdgcn_s_setprio(1);
#pragma unroll
        for (int j = 0; j < 2; j++) bn_[j] = neg8(bvi[j]);
#pragma unroll
        for (int i = 0; i < 2; i++)
#pragma unroll
            for (int j = 0; j < 2; j++) {
                accr[2][i][j] = MFMA16(ar[i],  bvr[j], accr[2][i][j]);
                accr[2][i][j] = MFMA16(ai_[i], bn_[j], accr[2][i][j]);
                acci[2][i][j] = MFMA16(ar[i],  bvi[j], acci[2][i][j]);
                acci[2][i][j] = MFMA16(ai_[i], bvr[j], acci[2][i][j]);
            }
        __builtin_amdgcn_s_setprio(0);
        // no trailing barrier: next step opens with vmcnt+barrier
    };

    // prologue: tiles 0,1 fully staged
#pragma unroll
    for (int j = 0; j < 5; j++) stage1(smem,         j, 0);
#pragma unroll
    for (int j = 0; j < 5; j++) stage1(smem + 20480, j, 32);

    for (int base = 0; base < 30; base += 3) {
        step(BC<true>{}, BC<false>{}, 0, 2, (base + 2) * 32);
        step(BC<true>{}, BC<false>{}, 1, 0, (base + 3) * 32);
        step(BC<true>{}, BC<false>{}, 2, 1, (base + 4) * 32);
    }
    step(BC<false>{}, BC<false>{}, 0, 0, 0);
    step(BC<false>{}, BC<true >{}, 1, 0, 0);

    const int bb = m0 >> 10, tbase = m0 & (T_SEQ - 1);

    // ---- Q and K: RoPE + bias, write [B,H,T,64] via LDS bounce ----
#pragma unroll
    for (int p = 0; p < 2; p++) {
        const float* bias = p ? bk : bq;
#pragma unroll
        for (int i = 0; i < 2; i++)
#pragma unroll
            for (int j = 0; j < 2; j++) {
                int d = wn + j * 16 + lm;
                float2 bvv = *(const float2*)&bias[2 * (n0 + d)];
#pragma unroll
                for (int r = 0; r < 4; r++) {
                    int tpos = tbase + wm + i * 16 + quad * 4 + r;
                    float2 ph = *(const float2*)&rope[((size_t)tpos * H_DIM + d) * 2];
                    float yr = accr[p][i][j][r] + bvv.x;
                    float yi = acci[p][i][j][r] + bvv.y;
                    accr[p][i][j][r] = yr * ph.x - yi * ph.y;
                    acci[p][i][j][r] = yr * ph.y + yi * ph.x;
                }
            }
        bf16* dr = (p ? Kr : Qr) + ((size_t)(bb * NH_ + h) * T_SEQ + tbase) * H_DIM;
        bf16* di = (p ? Ki : Qi) + ((size_t)(bb * NH_ + h) * T_SEQ + tbase) * H_DIM;
#pragma unroll
        for (int pass = 0; pass < 2; pass++) {
            __syncthreads();
#pragma unroll
            for (int i = 0; i < 2; i++)
#pragma unroll
                for (int j = 0; j < 2; j++)
#pragma unroll
                    for (int r = 0; r < 4; r++)
                        smem[(wm + i * 16 + quad * 4 + r) * 72 + wn + j * 16 + lm] =
                            (bf16)(pass ? acci[p][i][j][r] : accr[p][i][j][r]);
            __syncthreads();
            bf16* dst = pass ? di : dr;
#pragma unroll
            for (int pp = 0; pp < 2; pp++) {
                int ch = t + 512 * pp;              // 1024 chunks: 128 rows x 8
                int row = ch >> 3, o = (ch & 7) * 8;
                *(bf16x8*)&dst[row * H_DIM + o] = *(const bf16x8*)&smem[row * 72 + o];
            }
        }
    }

    // ---- V: bias, transpose-write [B,H,64,T] via LDS bounce ----
    {
#pragma unroll
        for (int pass = 0; pass < 2; pass++) {
            __syncthreads();
#pragma unroll
            for (int i = 0; i < 2; i++)
#pragma unroll
                for (int j = 0; j < 2; j++) {
                    int d = wn + j * 16 + lm;
                    float2 bvv = *(const float2*)&bv[2 * (n0 + d)];
                    float bb2 = pass ? bvv.y : bvv.x;
                    bf16x4 pk;
#pragma unroll
                    for (int r = 0; r < 4; r++)
                        pk[r] = (bf16)((pass ? acci[2][i][j][r] : accr[2][i][j][r]) + bb2);
                    *(bf16x4*)&smem[d * 136 + wm + i * 16 + quad * 4] = pk;
                }
            __syncthreads();
            bf16* dst = (pass ? Vi : Vr) + ((size_t)(bb * NH_ + h) * H_DIM) * T_SEQ + tbase;
#pragma unroll
            for (int pp = 0; pp < 2; pp++) {
                int ch = t + 512 * pp;              // 1024 chunks: 64 rows x 16
                int row = ch >> 4, o = (ch & 15) * 8;
                *(bf16x8*)&dst[(size_t)row * T_SEQ + o] = *(const bf16x8*)&smem[row * 136 + o];
            }
        }
    }
}

// ---------------------------------------------------------------------------
// 64x64 complex GEMM, BK=64, single-buffer (round-0/1 proven form).
// ---------------------------------------------------------------------------
__global__ __launch_bounds__(256, 4)
void out_gemm(const bf16* __restrict__ Ar, const bf16* __restrict__ Ai,
              const bf16* __restrict__ Br, const bf16* __restrict__ Bi,
              const float* __restrict__ bias, float* __restrict__ Y)
{
    __shared__ __attribute__((aligned(16))) bf16 sm[16384];   // 32 KB
    const int t = threadIdx.x, lane = t & 63, wave = t >> 6;
    const int lm = lane & 15, quad = lane >> 4;
    const int s_lr = lane >> 3, s_c = (lane & 7) ^ s_lr;
    const int wm = (wave >> 1) * 32, wn = (wave & 1) * 32;
    const int m0 = blockIdx.y * 64, n0 = blockIdx.x * 64;

    f32x4 accr[2][2], acci[2][2];
#pragma unroll
    for (int i = 0; i < 2; i++)
#pragma unroll
        for (int j = 0; j < 2; j++) { accr[i][j] = (f32x4)0.f; acci[i][j] = (f32x4)0.f; }

    for (int k0 = 0; k0 < C_DIM; k0 += 64) {
#pragma unroll
        for (int j = 0; j < 8; j++) {
            int c = wave + 4 * j;
            const bf16* src; bf16* dst;
            if (c < 8)       {             src = Ar + (size_t)(m0 + c * 8 + s_lr) * C_DIM + k0 + s_c * 8; dst = sm + c * 512; }
            else if (c < 16) { int u = c - 8;  src = Ai + (size_t)(m0 + u * 8 + s_lr) * C_DIM + k0 + s_c * 8; dst = sm + 4096 + u * 512; }
            else if (c < 24) { int u = c - 16; src = Br + (size_t)(n0 + u * 8 + s_lr) * C_DIM + k0 + s_c * 8; dst = sm + 8192 + u * 512; }
            else             { int u = c - 24; src = Bi + (size_t)(n0 + u * 8 + s_lr) * C_DIM + k0 + s_c * 8; dst = sm + 12288 + u * 512; }
            GLOAD_LDS16(src, dst);
        }
        __syncthreads();
#pragma unroll
        for (int kh = 0; kh < 2; kh++) {
            bf16x8 ar[2], ai_[2], br_[2], bi_[2], bn_[2];
#pragma unroll
            for (int i = 0; i < 2; i++) {
                ar[i]  = frag_sw(sm,        wm + i * 16 + lm, kh * 4 + quad);
                ai_[i] = frag_sw(sm + 4096, wm + i * 16 + lm, kh * 4 + quad);
            }
#pragma unroll
            for (int j = 0; j < 2; j++) {
                br_[j] = frag_sw(sm + 8192,  wn + j * 16 + lm, kh * 4 + quad);
                bi_[j] = frag_sw(sm + 12288, wn + j * 16 + lm, kh * 4 + quad);
                bn_[j] = neg8(bi_[j]);
            }
#pragma unroll
            for (int i = 0; i < 2; i++)
#pragma unroll
                for (int j = 0; j < 2; j++) {
                    accr[i][j] = MFMA16(ar[i],  br_[j], accr[i][j]);
                    accr[i][j] = MFMA16(ai_[i], bn_[j], accr[i][j]);
                    acci[i][j] = MFMA16(ar[i],  bi_[j], acci[i][j]);
                    acci[i][j] = MFMA16(ai_[i], br_[j], acci[i][j]);
                }
        }
        __syncthreads();
    }
#pragma unroll
    for (int i = 0; i < 2; i++)
#pragma unroll
        for (int j = 0; j < 2; j++) {
            int n = n0 + wn + j * 16 + lm;
            float2 bvv = *(const float2*)&bias[2 * n];
#pragma unroll
            for (int r = 0; r < 4; r++) {
                int m = m0 + wm + i * 16 + quad * 4 + r;
                *(float2*)&Y[((size_t)m * C_DIM + n) * 2] =
                    make_float2(accr[i][j][r] + bvv.x, acci[i][j][r] + bvv.y);
            }
        }
}

// ---------------------------------------------------------------------------
// MFMA flash attention v3 — round-1 internals; grid (h, q, b) so all 16
// q-blocks of a head land on XCD h%8 and the head's K/V stays L2-resident.
// ---------------------------------------------------------------------------
__global__ __launch_bounds__(512, 4)
void attn_mfma(const bf16* __restrict__ Qpr, const bf16* __restrict__ Qpi,
               const bf16* __restrict__ Kpr, const bf16* __restrict__ Kpi,
               const bf16* __restrict__ Vtr, const bf16* __restrict__ Vti,
               bf16* __restrict__ ABr, bf16* __restrict__ ABi)
{
    __shared__ __attribute__((aligned(16))) bf16 smem[32768];  // 64 KB
    const int t = threadIdx.x, lane = t & 63, w = t >> 6;
    const int qg = w & 3, sh = w >> 2;
    const int lm = lane & 15, quad = lane >> 4;
    const int h = blockIdx.x;                  // x = head (XCD pin)
    const int q0 = blockIdx.y * 64;            // y = q-tile
    const int b = blockIdx.z;
    const size_t hb = (size_t)(b * NH_ + h) * T_SEQ * H_DIM;
    const int s_lr = lane >> 3, s_c = (lane & 7) ^ s_lr;
    const int lr4 = lane >> 2, sc4a = ((lane & 3) ^ (lr4 & 3)) * 8;

    // stage Q (64x64 per plane) into buf1 region, then hold frags in regs
    {
        const bf16* gq = (sh ? Qpi : Qpr) + hb + (size_t)q0 * H_DIM;
        bf16* lq = smem + 16384 + sh * 4096;
#pragma unroll
        for (int j = 0; j < 2; j++) {
            int cc = qg * 2 + j;
            GLOAD_LDS16(gq + (cc * 8 + s_lr) * H_DIM + s_c * 8, lq + cc * 512);
        }
    }
    __syncthreads();

    bf16x8 qfr[2], qfi[2], nqfr[2];
#pragma unroll
    for (int kh = 0; kh < 2; kh++) {
        qfr[kh]  = frag_sw(smem + 16384, qg * 16 + lm, kh * 4 + quad);
        qfi[kh]  = frag_sw(smem + 20480, qg * 16 + lm, kh * 4 + quad);
        nqfr[kh] = neg8(qfr[kh]);
    }

    // stage tile 0 into buf0 (per-wave plane assignment)
#pragma unroll
    for (int pre = 0; pre < 1; pre++) {
        const int S = sh * 512;
        bf16* bd = smem + sh * 8192;
        if (qg < 2) {
            const bf16* g = (qg ? Kpi : Kpr) + hb + (size_t)S * H_DIM;
            bf16* d = bd + (qg ? 2048 : 0);
#pragma unroll
            for (int cc = 0; cc < 4; cc++)
                GLOAD_LDS16(g + (cc * 8 + s_lr) * H_DIM + s_c * 8, d + cc * 512);
        } else {
            const bf16* g = (qg == 2 ? Vtr : Vti) + hb + S;
            bf16* d = bd + (qg == 2 ? 4096 : 6144);
#pragma unroll
            for (int cc = 0; cc < 4; cc++)
                GLOAD_LDS16(g + (size_t)(cc * 16 + lr4) * T_SEQ + sc4a, d + cc * 512);
        }
    }

    f32x4 Or[4], Oi[4];
#pragma unroll
    for (int nt = 0; nt < 4; nt++) { Or[nt] = (f32x4)0.f; Oi[nt] = (f32x4)0.f; }
    float lsum = 0.f;
    const int idxA = (((2 * quad) & 3) * 16 + lm) * 4;   // bpermute byte idx
    const int idxB = idxA + 64;
    const bool hisel = quad >= 2;

    for (int it = 0; it < 16; it++) {
        __syncthreads();   // drains stage(it) issued last iter
        if (it < 15) {     // stage tile it+1 into the other buffer
            const int S = (it + 1) * 32 + sh * 512;
            bf16* bd = smem + ((it + 1) & 1) * 16384 + sh * 8192;
            if (qg < 2) {
                const bf16* g = (qg ? Kpi : Kpr) + hb + (size_t)S * H_DIM;
                bf16* d = bd + (qg ? 2048 : 0);
#pragma unroll
                for (int cc = 0; cc < 4; cc++)
                    GLOAD_LDS16(g + (cc * 8 + s_lr) * H_DIM + s_c * 8, d + cc * 512);
            } else {
                const bf16* g = (qg == 2 ? Vtr : Vti) + hb + S;
                bf16* d = bd + (qg == 2 ? 4096 : 6144);
#pragma unroll
                for (int cc = 0; cc < 4; cc++)
                    GLOAD_LDS16(g + (size_t)(cc * 16 + lr4) * T_SEQ + sc4a, d + cc * 512);
            }
        }
        const bf16* buf = smem + (it & 1) * 16384 + sh * 8192;

        // ---- S^T scores (A = K frags, B = Q frags), p = exp2(|s|*SCL) ----
        union { unsigned int u[2]; bf16 b[4]; } pk[2];
        float lsA = 0.f, lsB = 0.f;
#pragma unroll
        for (int ct = 0; ct < 2; ct++) {
            f32x4 sre = (f32x4)0.f, sim = (f32x4)0.f;
            __builtin_amdgcn_s_setprio(1);
#pragma unroll
            for (int kh = 0; kh < 2; kh++) {
                bf16x8 kr = frag_sw(buf,        ct * 16 + lm, kh * 4 + quad);
                bf16x8 ki = frag_sw(buf + 2048, ct * 16 + lm, kh * 4 + quad);
                sre = MFMA16(kr, qfr[kh],  sre);
                sre = MFMA16(ki, qfi[kh],  sre);
                sim = MFMA16(kr, qfi[kh],  sim);
                sim = MFMA16(ki, nqfr[kh], sim);
            }
            __builtin_amdgcn_s_setprio(0);
#pragma unroll
            for (int r = 0; r < 4; r++) {
                float mag2 = fmaf(sre[r], sre[r], sim[r] * sim[r]);
                float p = __builtin_amdgcn_exp2f(__builtin_amdgcn_sqrtf(mag2) * SCL);
                if (ct) lsB += p; else lsA += p;
                pk[ct].b[r] = (bf16)p;
            }
        }
        lsum += lsA + lsB;

        // ---- P C-layout -> A-layout via bpermute (no LDS round trip) ----
        union { unsigned int u[4]; bf16x8 v; } pf;
        {
            int a0 = __builtin_amdgcn_ds_bpermute(idxA, (int)pk[0].u[0]);
            int a1 = __builtin_amdgcn_ds_bpermute(idxA, (int)pk[1].u[0]);
            int b0 = __builtin_amdgcn_ds_bpermute(idxA, (int)pk[0].u[1]);
            int b1 = __builtin_amdgcn_ds_bpermute(idxA, (int)pk[1].u[1]);
            int c0 = __builtin_amdgcn_ds_bpermute(idxB, (int)pk[0].u[0]);
            int c1 = __builtin_amdgcn_ds_bpermute(idxB, (int)pk[1].u[0]);
            int d0 = __builtin_amdgcn_ds_bpermute(idxB, (int)pk[0].u[1]);
            int d1 = __builtin_amdgcn_ds_bpermute(idxB, (int)pk[1].u[1]);
            pf.u[0] = (unsigned int)(hisel ? a1 : a0);
            pf.u[1] = (unsigned int)(hisel ? b1 : b0);
            pf.u[2] = (unsigned int)(hisel ? c1 : c0);
            pf.u[3] = (unsigned int)(hisel ? d1 : d0);
        }

        // ---- PV: O[q][d] += P @ V^T ----
        __builtin_amdgcn_s_setprio(1);
#pragma unroll
        for (int nt = 0; nt < 4; nt++) {
            Or[nt] = MFMA16(pf.v, frag_sw4(buf + 4096, nt * 16 + lm, quad), Or[nt]);
            Oi[nt] = MFMA16(pf.v, frag_sw4(buf + 6144, nt * 16 + lm, quad), Oi[nt]);
        }
        __builtin_amdgcn_s_setprio(0);
    }

    // reduce lsum across quads
    lsum += __shfl_xor(lsum, 16);
    lsum += __shfl_xor(lsum, 32);

    // merge the two s-halves: sh1 dumps to LDS, sh0 adds, normalizes, writes
    __syncthreads();
    float* Of  = (float*)smem;             // 128 rows x 66 floats (~33 KB)
    float* lsc = Of + 128 * 66;            // 64 floats
    if (sh == 1) {
#pragma unroll
        for (int nt = 0; nt < 4; nt++)
#pragma unroll
            for (int r = 0; r < 4; r++) {
                Of[((qg * 2 + 0) * 16 + quad * 4 + r) * 66 + nt * 16 + lm] = Or[nt][r];
                Of[((qg * 2 + 1) * 16 + quad * 4 + r) * 66 + nt * 16 + lm] = Oi[nt][r];
            }
        if (quad == 0) lsc[qg * 16 + lm] = lsum;
    }
    __syncthreads();
    if (sh == 0) {
        float ltot = lsum + lsc[qg * 16 + lm];
        float lv = 1.f / ltot;
        float linv[4];
#pragma unroll
        for (int r = 0; r < 4; r++)
            linv[r] = __shfl(lv, (quad << 4) + quad * 4 + r, 64);
        size_t mbase = (size_t)(b * T_SEQ + q0 + qg * 16 + quad * 4) * C_DIM;
        int colb = h * H_DIM + lm;
#pragma unroll
        for (int nt = 0; nt < 4; nt++)
#pragma unroll
            for (int r = 0; r < 4; r++) {
                float orv = Or[nt][r] + Of[((qg * 2 + 0) * 16 + quad * 4 + r) * 66 + nt * 16 + lm];
                float oiv = Oi[nt][r] + Of[((qg * 2 + 1) * 16 + quad * 4 + r) * 66 + nt * 16 + lm];
                size_t o = mbase + (size_t)r * C_DIM + colb + nt * 16;
                ABr[o] = (bf16)(orv * linv[r]);
                ABi[o] = (bf16)(oiv * linv[r]);
            }
    }
}

// ---------------------------------------------------------------------------
extern "C" void kernel_launch(void* const* d_in, const int* in_sizes, int n_in,
                              void* d_out, int out_size, void* d_ws, size_t ws_size,
                              hipStream_t stream) {
    const float* x  = (const float*)d_in[0];
    const float* wq = (const float*)d_in[1];
    const float* bq = (const float*)d_in[2];
    const float* wk = (const float*)d_in[3];
    const float* bk = (const float*)d_in[4];
    const float* wv = (const float*)d_in[5];
    const float* bv = (const float*)d_in[6];
    const float* wo = (const float*)d_in[7];
    const float* bo = (const float*)d_in[8];

    float* rope = (float*)d_ws;                       // 131072 floats (512 KB)
    bf16* w = (bf16*)(rope + 131072);
    const size_t MSZ = (size_t)2048 * 1024;
    const size_t WSZ = (size_t)1024 * 1024;
    const size_t PSZ = (size_t)2 * NH_ * T_SEQ * H_DIM;

    bf16 *Xr = w, *Xi = Xr + MSZ;
    bf16 *Wqr = Xi + MSZ,  *Wqi = Wqr + WSZ;
    bf16 *Wkr = Wqi + WSZ, *Wki = Wkr + WSZ;
    bf16 *Wvr = Wki + WSZ, *Wvi = Wvr + WSZ;
    bf16 *Wor = Wvi + WSZ, *Woi = Wor + WSZ;
    bf16 *Qr = Woi + WSZ, *Qi = Qr + PSZ;
    bf16 *Kr = Qi + PSZ,  *Ki = Kr + PSZ;
    bf16 *Vr = Ki + PSZ,  *Vi = Vr + PSZ;
    bf16 *ABr = Vi + PSZ, *ABi = ABr + MSZ;

    split_all<<<dim3(1024, 6), 256, 0, stream>>>(x, wq, wk, wv, wo,
        Xr, Xi, Wqr, Wqi, Wkr, Wki, Wvr, Wvi, Wor, Woi, rope);

    qkv_gemm<<<dim3(16, 16), 512, 0, stream>>>(
        Xr, Xi, Wqr, Wqi, Wkr, Wki, Wvr, Wvi, bq, bk, bv, rope,
        Qr, Qi, Kr, Ki, Vr, Vi);

    attn_mfma<<<dim3(16, 16, 2), 512, 0, stream>>>(
        Qr, Qi, Kr, Ki, Vr, Vi, ABr, ABi);

    out_gemm<<<dim3(16, 32), 256, 0, stream>>>(ABr, ABi, Wor, Woi, bo, (float*)d_out);
}